// Round 4
// baseline (113.349 us; speedup 1.0000x reference)
//
#include <hip/hip_runtime.h>
#include <math.h>

// k1 (seg_starts): starts[r] = first sample index of ray r, starts[N] = M.
//     int4-vectorized coalesced pass over ray_id (4 elems/thread).
// k2 (voxel_march): one wave per ray, 4 samples/lane (256-sample chunks),
//     register double-buffered: chunk i+1's loads issue before chunk i's
//     compute, hiding vmem latency under the shuffle ladder (typical ray =
//     exactly 2 chunks). Branchless edge masking: address-safe clamped loads,
//     invalid samples -> density -1e30 -> om=1, alpha=0, weight=0.
//
// Math: om = exp(-0.5*softplus(x)) = rsqrt(1+exp(x)); alpha = 1-om.
// out = sum w*sigmoid(rgb) + alphainv_last (white background).

__device__ __forceinline__ float sigm(float x) {
    return __builtin_amdgcn_rcpf(1.0f + __expf(-x));
}

__global__ __launch_bounds__(256) void seg_starts_kernel(
    const int* __restrict__ ray_id, int* __restrict__ starts, int M, int N)
{
    const int i4 = (blockIdx.x * 256 + threadIdx.x) * 4;
    if (i4 >= M) return;

    if (i4 + 3 < M) {
        const int4 v = *(const int4*)(ray_id + i4);
        const int prev = (i4 == 0) ? -1 : ray_id[i4 - 1];
        int c0 = prev, c1 = v.x, c2 = v.y, c3 = v.z, c4 = v.w;
        for (int r = c0 + 1; r <= c1; ++r) starts[r] = i4 + 0;
        for (int r = c1 + 1; r <= c2; ++r) starts[r] = i4 + 1;
        for (int r = c2 + 1; r <= c3; ++r) starts[r] = i4 + 2;
        for (int r = c3 + 1; r <= c4; ++r) starts[r] = i4 + 3;
        if (i4 + 4 == M) {
            for (int r = c4 + 1; r <= N; ++r) starts[r] = M;  // tail + sentinel
        }
    } else {
        // generic tail (M not multiple of 4)
        int prev = (i4 == 0) ? -1 : ray_id[i4 - 1];
        for (int k = 0; k < 4 && i4 + k < M; ++k) {
            const int cur = ray_id[i4 + k];
            for (int r = prev + 1; r <= cur; ++r) starts[r] = i4 + k;
            prev = cur;
            if (i4 + k == M - 1)
                for (int r = cur + 1; r <= N; ++r) starts[r] = M;
        }
    }
}

__global__ __launch_bounds__(256) void voxel_march_kernel(
    const float* __restrict__ density,
    const float* __restrict__ rgb_raw,
    const float* __restrict__ shift,
    const int*   __restrict__ starts,
    float* __restrict__ out,
    int M, int N)
{
    const int lane = threadIdx.x & 63;
    const int wave = threadIdx.x >> 6;
    const int ray  = blockIdx.x * 4 + wave;
    if (ray >= N) return;

    const float sh = shift[0];
    const int begin = starts[ray];
    const int end   = starts[ray + 1];

    float carry = 1.0f;
    float acc0 = 0.0f, acc1 = 0.0f, acc2 = 0.0f;

    // register double buffers
    float4 dA, a0A, a1A, a2A;
    float4 dB, a0B, a1B, a2B;

    auto issue = [&](int base, float4& dd, float4& r0, float4& r1, float4& r2) {
        const int b4 = base + 4 * lane;
        const int ba = min(b4, M - 4);           // address-safe
        dd = *(const float4*)(density + ba);
        const float4* rp = (const float4*)(rgb_raw + 3 * ba);
        r0 = rp[0]; r1 = rp[1]; r2 = rp[2];
    };

    auto compute = [&](int base, const float4& dd, const float4& c0,
                       const float4& c1, const float4& c2) {
        const int b4 = base + 4 * lane;
        const bool v0 = (b4 + 0 >= begin) & (b4 + 0 < end);
        const bool v1 = (b4 + 1 >= begin) & (b4 + 1 < end);
        const bool v2 = (b4 + 2 >= begin) & (b4 + 2 < end);
        const bool v3 = (b4 + 3 >= begin) & (b4 + 3 < end);
        const float d0 = v0 ? dd.x : -1e30f;
        const float d1 = v1 ? dd.y : -1e30f;
        const float d2 = v2 ? dd.z : -1e30f;
        const float d3 = v3 ? dd.w : -1e30f;

        const float om0 = __builtin_amdgcn_rsqf(1.0f + __expf(d0 + sh));
        const float om1 = __builtin_amdgcn_rsqf(1.0f + __expf(d1 + sh));
        const float om2 = __builtin_amdgcn_rsqf(1.0f + __expf(d2 + sh));
        const float om3 = __builtin_amdgcn_rsqf(1.0f + __expf(d3 + sh));
        const float al0 = 1.0f - om0, al1 = 1.0f - om1;
        const float al2 = 1.0f - om2, al3 = 1.0f - om3;

        // wave-wide inclusive cumprod over lane products
        float p = (om0 * om1) * (om2 * om3);
        #pragma unroll
        for (int off = 1; off < 64; off <<= 1) {
            float q = __shfl_up(p, off, 64);
            if (lane >= off) p *= q;
        }
        float excl = __shfl_up(p, 1, 64);
        if (lane == 0) excl = 1.0f;

        float t = carry * excl;
        const float w0 = al0 * t; t *= om0;
        const float w1 = al1 * t; t *= om1;
        const float w2 = al2 * t; t *= om2;
        const float w3 = al3 * t;

        acc0 += w0 * sigm(c0.x) + w1 * sigm(c0.w) + w2 * sigm(c1.z) + w3 * sigm(c2.y);
        acc1 += w0 * sigm(c0.y) + w1 * sigm(c1.x) + w2 * sigm(c1.w) + w3 * sigm(c2.z);
        acc2 += w0 * sigm(c0.z) + w1 * sigm(c1.y) + w2 * sigm(c2.x) + w3 * sigm(c2.w);

        carry *= __shfl(p, 63, 64);
    };

    int base = begin & ~3;
    if (base < end) {
        issue(base, dA, a0A, a1A, a2A);
        while (true) {
            int nb = base + 256;
            const bool moreB = nb < end;
            if (moreB) issue(nb, dB, a0B, a1B, a2B);   // prefetch before compute
            compute(base, dA, a0A, a1A, a2A);
            if (!moreB) break;
            base = nb;
            nb = base + 256;
            const bool moreA = nb < end;
            if (moreA) issue(nb, dA, a0A, a1A, a2A);
            compute(base, dB, a0B, a1B, a2B);
            if (!moreA) break;
            base = nb;
        }
    }

    // wave reduction
    #pragma unroll
    for (int off = 32; off > 0; off >>= 1) {
        acc0 += __shfl_down(acc0, off, 64);
        acc1 += __shfl_down(acc1, off, 64);
        acc2 += __shfl_down(acc2, off, 64);
    }

    if (lane == 0) {
        out[3 * ray + 0] = acc0 + carry;   // + alphainv_last
        out[3 * ray + 1] = acc1 + carry;
        out[3 * ray + 2] = acc2 + carry;
    }
}

extern "C" void kernel_launch(void* const* d_in, const int* in_sizes, int n_in,
                              void* d_out, int out_size, void* d_ws, size_t ws_size,
                              hipStream_t stream)
{
    const float* density = (const float*)d_in[0];
    const float* rgb_raw = (const float*)d_in[1];
    const float* shift   = (const float*)d_in[2];
    const int*   ray_id  = (const int*)d_in[3];
    float* out = (float*)d_out;

    const int M = in_sizes[0];
    const int N = out_size / 3;

    int* starts = (int*)d_ws;
    const int t1 = (M + 3) / 4;
    seg_starts_kernel<<<(t1 + 255) / 256, 256, 0, stream>>>(ray_id, starts, M, N);

    const int rays_per_block = 4;
    const int blocks = (N + rays_per_block - 1) / rays_per_block;
    voxel_march_kernel<<<blocks, 256, 0, stream>>>(density, rgb_raw, shift,
                                                   starts, out, M, N);
}